// Round 5
// baseline (1116.355 us; speedup 1.0000x reference)
//
#include <hip/hip_runtime.h>
#include <cmath>

typedef unsigned int uint32;
typedef _Float16 v2h __attribute__((ext_vector_type(2)));

__device__ __forceinline__ float fast_tanh(float x) {
    // tanh(x) = 1 - 2/(exp(2x)+1); correct saturation for large |x|
    float e = __expf(2.0f * x);
    return 1.0f - 2.0f * __builtin_amdgcn_rcpf(e + 1.0f);
}

__device__ __forceinline__ uint32 pkf(float x, float y) {
    v2h v; v.x = (_Float16)x; v.y = (_Float16)y;
    return __builtin_bit_cast(uint32, v);
}
__device__ __forceinline__ v2h bch(uint32 u) { return __builtin_bit_cast(v2h, u); }

__device__ __forceinline__ float dot2(v2h a, v2h b, float c) {
#if __has_builtin(__builtin_amdgcn_fdot2)
    return __builtin_amdgcn_fdot2(a, b, c, false);   // v_dot2_f32_f16, fp32 accum
#else
    return fmaf((float)a[0], (float)b[0], fmaf((float)a[1], (float)b[1], c));
#endif
}

// DPP-based add step: x += dpp_move(x, CTRL); bound_ctrl=true -> invalid lanes give 0.
template <int CTRL>
__device__ __forceinline__ float dpp_radd(float x) {
    int t = __builtin_amdgcn_update_dpp(0, __builtin_bit_cast(int, x),
                                        CTRL, 0xf, 0xf, true);
    return x + __builtin_bit_cast(float, t);
}
// Full wave64 sum -> lane 63, broadcast via readlane (uniform SGPR).
__device__ __forceinline__ float wave_sum_bcast(float x) {
    x = dpp_radd<0x111>(x);   // row_shr:1
    x = dpp_radd<0x112>(x);   // row_shr:2
    x = dpp_radd<0x114>(x);   // row_shr:4
    x = dpp_radd<0x118>(x);   // row_shr:8
    x = dpp_radd<0x142>(x);   // row_bcast:15
    x = dpp_radd<0x143>(x);   // row_bcast:31
    int s = __builtin_amdgcn_readlane(__builtin_bit_cast(int, x), 63);
    return __builtin_bit_cast(float, s);
}

// TWO waves (128 threads) integrate one batch row: thread t owns hidden unit t
// in both layers (W2 row t = 64 packed-fp16 VGPRs). Two LDS exchanges/stage
// (h1, h2), RK4 state redundant in registers in every thread.
__global__ __launch_bounds__(128, 2) void node_kernel(
    const float* __restrict__ y0,        // [B]
    const float* __restrict__ latent,    // [B,32]
    const int*   __restrict__ length,    // [B]
    const float* __restrict__ dense_cs,  // [B,D]
    const float* __restrict__ W1,        // [128,43]
    const float* __restrict__ b1,        // [128]
    const float* __restrict__ W2,        // [128,128]
    const float* __restrict__ b2,        // [128]
    const float* __restrict__ W3,        // [41,128]
    const float* __restrict__ b3,        // [41]
    float* __restrict__ out,             // [B,T]
    int T, int D)
{
    const int tid  = threadIdx.x;        // 0..127: hidden unit owned
    const int lane = tid & 63;
    const int row  = blockIdx.x;

    __shared__ __align__(16) _Float16 s_h1[128];
    __shared__ __align__(16) _Float16 s_h2[128];
    __shared__ __align__(16) float    s_cs[256];

    // stage this row's concentration series
    for (int q = tid; q < D; q += 128) s_cs[q] = dense_cs[row * D + q];

    // ---- W2 row tid -> 64 packed fp16 pairs, pinned in VGPRs ----
    uint32 w2r[64];
    {
        const float2* r0 = reinterpret_cast<const float2*>(W2 + tid * 128);
#pragma unroll
        for (int k = 0; k < 64; ++k) { float2 f = r0[k]; w2r[k] = pkf(f.x, f.y); }
    }
#pragma unroll
    for (int k = 0; k < 64; ++k) asm volatile("" : "+v"(w2r[k]));

    // ---- W1 row tid (state cols + t + c) + layer-1 constant ----
    const float* W1r = W1 + tid * 43;
    float w1r[11];
#pragma unroll
    for (int d = 0; d < 9; ++d) w1r[d] = W1r[d];
    w1r[9]  = W1r[41];   // time col
    w1r[10] = W1r[42];   // concentration col

    const float* lat = latent + row * 32;
    float c1 = b1[tid];
#pragma unroll
    for (int l = 0; l < 32; ++l) c1 = fmaf(W1r[9 + l], lat[l], c1);
    const float b2t = b2[tid];
#pragma unroll
    for (int d = 0; d < 11; ++d) asm volatile("" : "+v"(w1r[d]));

    // ---- layer-3: lane owns h2 pair (2*lane, 2*lane+1); same in both waves ----
    uint32 w3p[9]; float b3r[9];
#pragma unroll
    for (int i = 0; i < 9; ++i) {
        w3p[i] = pkf(W3[i * 128 + 2 * lane], W3[i * 128 + 2 * lane + 1]);
        b3r[i] = b3[i];
        asm volatile("" : "+v"(w3p[i]));
    }

    // ---- RK4 state, redundant (identical) in every thread ----
    const float y00 = y0[row];
    float Y[9], K[9], Ys[9];
#pragma unroll
    for (int i = 0; i < 9; ++i) { Y[i] = (i == 0) ? y00 : 0.0f; Ys[i] = Y[i]; K[i] = 0.0f; }

    int len = length[row] - 1;
    if (len < 0) len = 0;
    const float tend = (float)len;       // ts = arange
    if (tid == 0) out[row * T] = y00;
    __syncthreads();                     // covers s_cs staging

    const int nsub = (T - 1) * 2;
    for (int step = 0; step < nsub; ++step) {
        const float t0 = 0.5f * (float)step;   // exact

        // ---- dead-row fast path (block-uniform): vf == 0 forever after tend ----
        if (t0 > tend) {
            const float yv = Y[0];
            for (int i = (step >> 1) + 1 + tid; i < T; i += 128)
                out[row * T + i] = yv;
            break;
        }

        // ---- concentration at the 3 distinct stage times ----
        float cv[3];
#pragma unroll
        for (int m = 0; m < 3; ++m) {
            const float tau = t0 + 0.25f * (float)m;
            int ii = (int)tau;
            int idx = ii + ((tau - (float)ii) > 0.0f ? 1 : 0);
            idx = min(max(idx, 1), D - 1);
            float w = tau - (float)(idx - 1);
            w = fminf(fmaxf(w, 0.0f), 1.0f);
            cv[m] = (1.0f - w) * s_cs[idx - 1] + w * s_cs[idx];
        }

#pragma unroll
        for (int s = 0; s < 4; ++s) {
            const float tau = t0 + ((s == 0) ? 0.0f : (s == 3) ? 0.5f : 0.25f);
            const float c   = cv[(s == 0) ? 0 : (s == 3) ? 2 : 1];

            // ---- layer 1: one hidden unit per thread ----
            float pre = fmaf(w1r[9], tau, c1);
            pre = fmaf(w1r[10], c, pre);
#pragma unroll
            for (int d = 0; d < 9; ++d) pre = fmaf(w1r[d], Ys[d], pre);
            s_h1[tid] = (_Float16)fast_tanh(pre);
            __syncthreads();   // B1: h1 ready

            // ---- layer 2: dot of W2 row tid with all 128 h1 (broadcast reads) ----
            uint4 hbuf[16];
            const uint4* s4 = reinterpret_cast<const uint4*>(s_h1);
#pragma unroll
            for (int q = 0; q < 16; ++q) hbuf[q] = s4[q];

            float a0 = 0.f, a1 = 0.f, a2 = 0.f, a3 = 0.f;
#pragma unroll
            for (int q = 0; q < 16; ++q) {
                a0 = dot2(bch(w2r[4 * q + 0]), bch(hbuf[q].x), a0);
                a1 = dot2(bch(w2r[4 * q + 1]), bch(hbuf[q].y), a1);
                a2 = dot2(bch(w2r[4 * q + 2]), bch(hbuf[q].z), a2);
                a3 = dot2(bch(w2r[4 * q + 3]), bch(hbuf[q].w), a3);
            }
            const float h2 = fast_tanh((a0 + a1) + (a2 + a3) + b2t);
            s_h2[tid] = (_Float16)h2;
            __syncthreads();   // B2: h2 ready

            // ---- layer 3: each wave reduces over all 128 units redundantly ----
            const uint32 hp = reinterpret_cast<const uint32*>(s_h2)[lane];
            float p[9];
#pragma unroll
            for (int i = 0; i < 9; ++i) p[i] = dot2(bch(w3p[i]), bch(hp), 0.0f);
#pragma unroll
            for (int i = 0; i < 9; ++i) p[i] = wave_sum_bcast(p[i]);

            // ---- vf finalize + RK4, identical in every thread ----
            const float alive = (tau <= tend) ? 1.0f : 0.0f;
            float kk[9];
            kk[0] = alive * (-__cosf(p[0] + b3r[0]));
#pragma unroll
            for (int i = 1; i < 9; ++i) kk[i] = alive * (p[i] + b3r[i]);

            if (s == 0) {
#pragma unroll
                for (int i = 0; i < 9; ++i) { K[i] = kk[i]; Ys[i] = fmaf(0.25f, kk[i], Y[i]); }
            } else if (s == 1) {
#pragma unroll
                for (int i = 0; i < 9; ++i) { K[i] = fmaf(2.0f, kk[i], K[i]); Ys[i] = fmaf(0.25f, kk[i], Y[i]); }
            } else if (s == 2) {
#pragma unroll
                for (int i = 0; i < 9; ++i) { K[i] = fmaf(2.0f, kk[i], K[i]); Ys[i] = fmaf(0.5f, kk[i], Y[i]); }
            } else {
#pragma unroll
                for (int i = 0; i < 9; ++i) {
                    K[i] = K[i] + kk[i];
                    Y[i] = fmaf(1.0f / 12.0f, K[i], Y[i]);  // dt/6 = 0.5/6
                    Ys[i] = Y[i];
                }
                if (tid == 0 && (step & 1)) out[row * T + (step >> 1) + 1] = Y[0];
            }
        }
    }
}

extern "C" void kernel_launch(void* const* d_in, const int* in_sizes, int n_in,
                              void* d_out, int out_size, void* d_ws, size_t ws_size,
                              hipStream_t stream) {
    // setup_inputs order:
    // 0 ts[T] 1 y0[B] 2 latent[B,32] 3 length[B] 4 dense_ts[D] 5 dense_cs[B,D]
    // 6 W1 7 b1 8 W2 9 b2 10 W3 11 b3
    const float* y0       = (const float*)d_in[1];
    const float* latent   = (const float*)d_in[2];
    const int*   length   = (const int*)  d_in[3];
    const float* dense_cs = (const float*)d_in[5];
    const float* W1 = (const float*)d_in[6];
    const float* b1 = (const float*)d_in[7];
    const float* W2 = (const float*)d_in[8];
    const float* b2 = (const float*)d_in[9];
    const float* W3 = (const float*)d_in[10];
    const float* b3 = (const float*)d_in[11];
    float* out = (float*)d_out;

    const int T = in_sizes[0];   // 128
    const int B = in_sizes[1];   // 1024
    const int D = in_sizes[4];   // 256

    node_kernel<<<B, 128, 0, stream>>>(y0, latent, length, dense_cs,
                                       W1, b1, W2, b2, W3, b3, out, T, D);
}

// Round 6
// 997.149 us; speedup vs baseline: 1.1195x; 1.1195x over previous
//
#include <hip/hip_runtime.h>
#include <cmath>

typedef unsigned int uint32;
typedef _Float16 v2h __attribute__((ext_vector_type(2)));

__device__ __forceinline__ float fast_tanh(float x) {
    // tanh(x) = 1 - 2/(exp(2x)+1); correct saturation for large |x|
    float e = __expf(2.0f * x);
    return 1.0f - 2.0f * __builtin_amdgcn_rcpf(e + 1.0f);
}

__device__ __forceinline__ uint32 pkf(float x, float y) {
    v2h v; v.x = (_Float16)x; v.y = (_Float16)y;
    return __builtin_bit_cast(uint32, v);
}
__device__ __forceinline__ v2h bch(uint32 u) { return __builtin_bit_cast(v2h, u); }

__device__ __forceinline__ float dot2(v2h a, v2h b, float c) {
#if __has_builtin(__builtin_amdgcn_fdot2)
    return __builtin_amdgcn_fdot2(a, b, c, false);   // v_dot2_f32_f16, fp32 accum
#else
    return fmaf((float)a[0], (float)b[0], fmaf((float)a[1], (float)b[1], c));
#endif
}

// DPP-based add step: x += dpp_move(x, CTRL); bound_ctrl=true -> invalid lanes give 0.
template <int CTRL>
__device__ __forceinline__ float dpp_radd(float x) {
    int t = __builtin_amdgcn_update_dpp(0, __builtin_bit_cast(int, x),
                                        CTRL, 0xf, 0xf, true);
    return x + __builtin_bit_cast(float, t);
}
// Full wave64 sum -> lane 63, broadcast via readlane (uniform SGPR).
__device__ __forceinline__ float wave_sum_bcast(float x) {
    x = dpp_radd<0x111>(x);   // row_shr:1
    x = dpp_radd<0x112>(x);   // row_shr:2
    x = dpp_radd<0x114>(x);   // row_shr:4
    x = dpp_radd<0x118>(x);   // row_shr:8
    x = dpp_radd<0x142>(x);   // row_bcast:15
    x = dpp_radd<0x143>(x);   // row_bcast:31
    int s = __builtin_amdgcn_readlane(__builtin_bit_cast(int, x), 63);
    return __builtin_bit_cast(float, s);
}

// One wave (64 lanes) integrates one batch row. Lane owns hidden units 2L,2L+1.
// h1 is exchanged via v_readlane -> SGPR broadcast (NO LDS in the stage loop);
// layer 2 runs on full-rate v_pk_fma_f16 with fp16 chain-8 accumulation.
__global__ __launch_bounds__(64, 1) void node_kernel(
    const float* __restrict__ y0,        // [B]
    const float* __restrict__ latent,    // [B,32]
    const int*   __restrict__ length,    // [B]
    const float* __restrict__ dense_cs,  // [B,D]
    const float* __restrict__ W1,        // [128,43]
    const float* __restrict__ b1,        // [128]
    const float* __restrict__ W2,        // [128,128]
    const float* __restrict__ b2,        // [128]
    const float* __restrict__ W3,        // [41,128]
    const float* __restrict__ b3,        // [41]
    float* __restrict__ out,             // [B,T]
    int T, int D)
{
    const int lane = threadIdx.x;        // 0..63
    const int row  = blockIdx.x;
    const int u0 = lane * 2, u1 = u0 + 1;

    __shared__ __align__(16) float s_cs[256];   // this row's concentration series

    // stage dense_cs
    if (D == 256) {
        reinterpret_cast<float4*>(s_cs)[lane] =
            reinterpret_cast<const float4*>(dense_cs + row * D)[lane];
    } else {
        for (int q = lane; q < D; q += 64) s_cs[q] = dense_cs[row * D + q];
    }

    // ---- W2 rows u0,u1 -> packed fp16, pinned in registers ----
    uint32 w2a[64], w2b[64];
    {
        const float2* r0 = reinterpret_cast<const float2*>(W2 + u0 * 128);
        const float2* r1 = reinterpret_cast<const float2*>(W2 + u1 * 128);
#pragma unroll
        for (int k = 0; k < 64; ++k) {
            float2 f0 = r0[k], f1 = r1[k];
            w2a[k] = pkf(f0.x, f0.y);
            w2b[k] = pkf(f1.x, f1.y);
        }
    }
#pragma unroll
    for (int k = 0; k < 64; ++k) {
        asm volatile("" : "+v"(w2a[k]));   // opaque: compiler cannot re-sink the loads
        asm volatile("" : "+v"(w2b[k]));
    }

    // ---- W1 rows (state cols + t + c), layer-1 constants ----
    const float* W1r0 = W1 + u0 * 43;
    const float* W1r1 = W1 + u1 * 43;
    float w1a[11], w1b[11];
#pragma unroll
    for (int d = 0; d < 9; ++d) { w1a[d] = W1r0[d]; w1b[d] = W1r1[d]; }
    w1a[9] = W1r0[41]; w1a[10] = W1r0[42];
    w1b[9] = W1r1[41]; w1b[10] = W1r1[42];

    const float* lat = latent + row * 32;
    float c1a = b1[u0], c1b = b1[u1];
#pragma unroll
    for (int l = 0; l < 32; ++l) {
        float lv = lat[l];
        c1a = fmaf(W1r0[9 + l], lv, c1a);
        c1b = fmaf(W1r1[9 + l], lv, c1b);
    }
    const float b2a = b2[u0], b2b = b2[u1];

    // ---- W3 columns (u0,u1) for 9 live outputs, packed fp16; biases fp32 ----
    uint32 w3p[9]; float b3r[9];
#pragma unroll
    for (int i = 0; i < 9; ++i) {
        w3p[i] = pkf(W3[i * 128 + u0], W3[i * 128 + u1]);
        b3r[i] = b3[i];
        asm volatile("" : "+v"(w3p[i]));
    }
#pragma unroll
    for (int d = 0; d < 11; ++d) {
        asm volatile("" : "+v"(w1a[d]));
        asm volatile("" : "+v"(w1b[d]));
    }

    // ---- RK4 state, redundant (uniform) in every lane ----
    const float y00 = y0[row];
    float Y[9], K[9], Ys[9];
#pragma unroll
    for (int i = 0; i < 9; ++i) { Y[i] = (i == 0) ? y00 : 0.0f; Ys[i] = Y[i]; K[i] = 0.0f; }

    int len = length[row] - 1;
    if (len < 0) len = 0;
    const float tend = (float)len;       // ts = arange
    if (lane == 0) out[row * T] = y00;
    __syncthreads();                     // covers the s_cs staging (single wave: cheap)

    const int nsub = (T - 1) * 2;
    for (int step = 0; step < nsub; ++step) {
        const float t0 = 0.5f * (float)step;   // exact

        // ---- dead-row fast path: vf == 0 for all remaining time (wave-uniform) ----
        if (t0 > tend) {
            const float yv = Y[0];
            for (int i = (step >> 1) + 1 + lane; i < T; i += 64)
                out[row * T + i] = yv;
            break;
        }

        // ---- concentration at the 3 distinct stage times (shared s=1,2) ----
        float cv[3];
#pragma unroll
        for (int m = 0; m < 3; ++m) {
            const float tau = t0 + 0.25f * (float)m;
            int ii = (int)tau;
            int idx = ii + ((tau - (float)ii) > 0.0f ? 1 : 0);
            idx = min(max(idx, 1), D - 1);
            float w = tau - (float)(idx - 1);
            w = fminf(fmaxf(w, 0.0f), 1.0f);
            cv[m] = (1.0f - w) * s_cs[idx - 1] + w * s_cs[idx];
        }

#pragma unroll
        for (int s = 0; s < 4; ++s) {
            const float tau = t0 + ((s == 0) ? 0.0f : (s == 3) ? 0.5f : 0.25f);
            const float c   = cv[(s == 0) ? 0 : (s == 3) ? 2 : 1];

            // ---- layer 1: this lane's two hidden units (registers only) ----
            float pa = fmaf(w1a[9], tau, c1a); pa = fmaf(w1a[10], c, pa);
            float pb = fmaf(w1b[9], tau, c1b); pb = fmaf(w1b[10], c, pb);
#pragma unroll
            for (int d = 0; d < 9; ++d) {
                pa = fmaf(w1a[d], Ys[d], pa);
                pb = fmaf(w1b[d], Ys[d], pb);
            }
            const int h1pk = (int)pkf(fast_tanh(pa), fast_tanh(pb));

            // ---- layer 2: readlane-broadcast h1 + v_pk_fma_f16 (fp16 chain-8 acc) ----
            // chunk c consumes h pairs 8c..8c+7; per row one fp16x2 chain per chunk.
            v2h accA[8], accB[8];
#pragma unroll
            for (int cc = 0; cc < 8; ++cc) {
                uint32 hs[8];
#pragma unroll
                for (int m = 0; m < 8; ++m)
                    hs[m] = (uint32)__builtin_amdgcn_readlane(h1pk, 8 * cc + m);
                v2h aA = (v2h)0.0f, aB = (v2h)0.0f;
#pragma unroll
                for (int m = 0; m < 8; ++m) {
                    const int k = 8 * cc + m;
                    aA = __builtin_elementwise_fma(bch(w2a[k]), bch(hs[m]), aA);
                    aB = __builtin_elementwise_fma(bch(w2b[k]), bch(hs[m]), aB);
                }
                accA[cc] = aA; accB[cc] = aB;
            }
            // merge 8 chains per row: packed tree (3 levels), then fp32 finish
            v2h tA0 = accA[0] + accA[1], tA1 = accA[2] + accA[3];
            v2h tA2 = accA[4] + accA[5], tA3 = accA[6] + accA[7];
            v2h uA = (tA0 + tA1) + (tA2 + tA3);
            v2h tB0 = accB[0] + accB[1], tB1 = accB[2] + accB[3];
            v2h tB2 = accB[4] + accB[5], tB3 = accB[6] + accB[7];
            v2h uB = (tB0 + tB1) + (tB2 + tB3);
            const float h2a = fast_tanh((float)uA.x + (float)uA.y + b2a);
            const float h2b = fast_tanh((float)uB.x + (float)uB.y + b2b);
            const uint32 h2p = pkf(h2a, h2b);

            // ---- layer 3: per-lane contribution + DPP wave reduction (VALU only) ----
            float p[9];
#pragma unroll
            for (int i = 0; i < 9; ++i) p[i] = dot2(bch(w3p[i]), bch(h2p), 0.0f);
#pragma unroll
            for (int i = 0; i < 9; ++i) p[i] = wave_sum_bcast(p[i]);

            // ---- vf finalize + RK4, uniform in every lane (registers only) ----
            const float alive = (tau <= tend) ? 1.0f : 0.0f;
            float kk[9];
            kk[0] = alive * (-__cosf(p[0] + b3r[0]));
#pragma unroll
            for (int i = 1; i < 9; ++i) kk[i] = alive * (p[i] + b3r[i]);

            if (s == 0) {
#pragma unroll
                for (int i = 0; i < 9; ++i) { K[i] = kk[i]; Ys[i] = fmaf(0.25f, kk[i], Y[i]); }
            } else if (s == 1) {
#pragma unroll
                for (int i = 0; i < 9; ++i) { K[i] = fmaf(2.0f, kk[i], K[i]); Ys[i] = fmaf(0.25f, kk[i], Y[i]); }
            } else if (s == 2) {
#pragma unroll
                for (int i = 0; i < 9; ++i) { K[i] = fmaf(2.0f, kk[i], K[i]); Ys[i] = fmaf(0.5f, kk[i], Y[i]); }
            } else {
#pragma unroll
                for (int i = 0; i < 9; ++i) {
                    K[i] = K[i] + kk[i];
                    Y[i] = fmaf(1.0f / 12.0f, K[i], Y[i]);  // dt/6 = 0.5/6
                    Ys[i] = Y[i];
                }
                if (lane == 0 && (step & 1)) out[row * T + (step >> 1) + 1] = Y[0];
            }
        }
    }
}

extern "C" void kernel_launch(void* const* d_in, const int* in_sizes, int n_in,
                              void* d_out, int out_size, void* d_ws, size_t ws_size,
                              hipStream_t stream) {
    // setup_inputs order:
    // 0 ts[T] 1 y0[B] 2 latent[B,32] 3 length[B] 4 dense_ts[D] 5 dense_cs[B,D]
    // 6 W1 7 b1 8 W2 9 b2 10 W3 11 b3
    const float* y0       = (const float*)d_in[1];
    const float* latent   = (const float*)d_in[2];
    const int*   length   = (const int*)  d_in[3];
    const float* dense_cs = (const float*)d_in[5];
    const float* W1 = (const float*)d_in[6];
    const float* b1 = (const float*)d_in[7];
    const float* W2 = (const float*)d_in[8];
    const float* b2 = (const float*)d_in[9];
    const float* W3 = (const float*)d_in[10];
    const float* b3 = (const float*)d_in[11];
    float* out = (float*)d_out;

    const int T = in_sizes[0];   // 128
    const int B = in_sizes[1];   // 1024
    const int D = in_sizes[4];   // 256

    node_kernel<<<B, 64, 0, stream>>>(y0, latent, length, dense_cs,
                                      W1, b1, W2, b2, W3, b3, out, T, D);
}